// Round 15
// baseline (1235.597 us; speedup 1.0000x reference)
//
#include <hip/hip_runtime.h>
#include <hip/hip_bf16.h>
#include <math.h>

#define BB  32
#define NN  256
#define TT  256
#define WW  32
#define HH  128
#define EMBD 64
#define NCLS 16
#define NE  8192

__device__ __forceinline__ float bf(const __hip_bfloat16* p, int i) {
    return __bfloat162float(p[i]);
}
__device__ __forceinline__ float ld3(const void* p, int i, int m) {
    if (m == 2) return (float)((const double*)p)[i];
    if (m == 1) return ((const float*)p)[i];
    return __bfloat162float(((const __hip_bfloat16*)p)[i]);
}
__device__ __forceinline__ float r16(float x) {
    return __bfloat162float(__float2bfloat16(x));
}
__device__ __forceinline__ float tanh_s(float x) {
    x = fminf(20.0f, fmaxf(-20.0f, x));
    return tanhf(x);
}
__device__ __forceinline__ float sig_s(float x) {
    x = fminf(30.0f, fmaxf(-30.0f, x));
    return 1.0f / (1.0f + expf(-x));
}

// ---------------- guards / dtype detection ----------------

__global__ __launch_bounds__(64) void k_sentinel(float* out, float v) {
    int i = blockIdx.x * 64 + threadIdx.x;
    if (i < BB * NCLS) out[i] = v;
}

__global__ __launch_bounds__(256) void k_probe_all(
        const void* x, const void* ew, const void* Wg, const void* W1, const void* W2,
        const void* Wz, const void* Wr, const void* Wh, const void* Wlz, const void* Wlr,
        const void* Wlh, const void* Wc, int* insB, int* insF) {
    int sec = blockIdx.x >> 2, sub = blockIdx.x & 3;
    const void* p; int nB, idx;
    switch (sec) {
        case 0:  p = x;   nB = 32768; idx = 0;  break;
        case 1:  p = ew;  nB = 8192;  idx = 2;  break;
        case 2:  p = Wg;  nB = 10240; idx = 3;  break;
        case 3:  p = W1;  nB = 4096;  idx = 5;  break;
        case 4:  p = W2;  nB = 4096;  idx = 7;  break;
        case 5:  p = Wz;  nB = 4096;  idx = 9;  break;
        case 6:  p = Wr;  nB = 4096;  idx = 11; break;
        case 7:  p = Wh;  nB = 4096;  idx = 13; break;
        case 8:  p = Wlz; nB = 32768; idx = 15; break;
        case 9:  p = Wlr; nB = 32768; idx = 17; break;
        case 10: p = Wlh; nB = 32768; idx = 19; break;
        default: p = Wc;  nB = 32768; idx = 21; break;
    }
    int nF = nB >> 2;
    const __hip_bfloat16* pb = (const __hip_bfloat16*)p;
    const float* pf = (const float*)p;
    int start = sub * 256 + threadIdx.x;
    for (int i = start; i < nB; i += 1024) {
        float v = __bfloat162float(pb[i]);
        if (!(fabsf(v) < 64.0f)) { insB[idx] = 1; break; }
    }
    for (int i = start; i < nF; i += 1024) {
        float v = pf[i];
        if (!(fabsf(v) < 1e4f)) { insF[idx] = 1; break; }
    }
}

__global__ void k_resolve(const int* insB, const int* insF, int* modes) {
    int i = threadIdx.x;
    if (i < 32 && i != 1)
        modes[i] = insB[i] ? (insF[i] ? 2 : 1) : 0;
}

__global__ __launch_bounds__(64) void k_detect_ei(const int* ei, int* modes) {
    if (threadIdx.x == 0 && blockIdx.x == 0) {
        bool allz = true;
        for (int k = 1; k < 64; k += 2) if (ei[k] != 0) allz = false;
        modes[1] = allz ? 1 : 0;
    }
}

__global__ __launch_bounds__(256) void k_cvtall(const void* Wg, const void* W1, const void* W2,
                                                const void* Wz, const void* Wr, const void* Wh,
                                                const void* Wlz, const void* Wlr, const void* Wlh,
                                                const void* Wc, const int* modes, float* dst) {
    int i = blockIdx.x * 256 + threadIdx.x;
    if (i >= 665600) return;
    float v;
    if      (i < 10240)  v = ld3(Wg,  i,          modes[3]);
    else if (i < 14336)  v = ld3(W1,  i - 10240,  modes[5]);
    else if (i < 18432)  v = ld3(W2,  i - 14336,  modes[7]);
    else if (i < 22528)  v = ld3(Wz,  i - 18432,  modes[9]);
    else if (i < 26624)  v = ld3(Wr,  i - 22528,  modes[11]);
    else if (i < 30720)  v = ld3(Wh,  i - 26624,  modes[13]);
    else if (i < 63488)  v = ld3(Wlz, i - 30720,  modes[15]);
    else if (i < 96256)  v = ld3(Wlr, i - 63488,  modes[17]);
    else if (i < 129024) v = ld3(Wlh, i - 96256,  modes[19]);
    else if (i < 653312) v = ld3(Wc,  i - 129024, modes[21]);
    else {
        int j = i - 653312, w = j / 384, rem = j - w * 384;
        int g = rem >> 7, f = rem & 127;
        const void* Wk = (g == 0) ? Wz : ((g == 1) ? Wr : Wh);
        int mk = (g == 0) ? modes[9] : ((g == 1) ? modes[11] : modes[13]);
        v = ld3(Wk, w * 128 + f, mk);
    }
    dst[i] = v;
}

// ---------------- setup: bf16 static graph ----------------

__global__ __launch_bounds__(256) void k_scatter(const int* ei, const void* ew, float* A,
                                                 const int* modes) {
    int e = blockIdx.x * 256 + threadIdx.x;
    if (e < NE) {
        int s, t;
        if (modes[1]) { s = ei[2 * e]; t = ei[2 * (NE + e)]; }
        else          { s = ei[e];     t = ei[NE + e]; }
        float w = r16(ld3(ew, e, modes[2]));
        if ((unsigned)s < NN && (unsigned)t < NN)
            atomicAdd(&A[s * NN + t], w);
    }
    if (blockIdx.x == 0) atomicAdd(&A[threadIdx.x * NN + threadIdx.x], 1.0f);
}

__global__ __launch_bounds__(256) void k_roundA(float* A) {
    int i = blockIdx.x * 256 + threadIdx.x;
    A[i] = r16(A[i]);
}

__global__ __launch_bounds__(256) void k_di(const float* A, float* di) {
    int wave = threadIdx.x >> 6, lane = threadIdx.x & 63;
    int c = blockIdx.x * 4 + wave;
    float s = 0.f;
    for (int r = lane; r < NN; r += 64) s += A[r * NN + c];
    for (int o = 32; o > 0; o >>= 1) s += __shfl_down(s, o, 64);
    if (lane == 0) {
        float deg = r16(s);
        di[c] = (deg > 0.f) ? r16(1.0f / sqrtf(deg)) : 0.0f;
    }
}

__global__ __launch_bounds__(256) void k_St(const float* A, const float* di, float* St) {
    int idx = blockIdx.x * 256 + threadIdx.x; // idx = c*NN + r
    int c = idx >> 8, r = idx & 255;
    St[idx] = r16(r16(di[r] * A[r * NN + c]) * di[c]);
}

// ---------------- per-step ----------------

// k1g: Y[row,f] = [vt|h] @ Wg; rows=B*N, K=160 (32 x-window + 128 h), tile 64x64
__global__ __launch_bounds__(256) void k1g(const void* x, const float* h, const float* Wgf,
                                           float* Y, int t, const int* modes) {
    __shared__ float As[32][68];
    __shared__ float Bs[32][68];
    int row0 = blockIdx.x * 64;
    int tid = threadIdx.x;
    int tn = tid & 15, tm = tid >> 4;
    int am = tid >> 2, ak0 = (tid & 3) * 8;
    int bk = tid >> 3, bn0 = (tid & 7) * 8;
    int rot = (tid & 3) * 2;
    int m0 = modes[0];
    float acc[4][4] = {};
    for (int kb = 0; kb < 160; kb += 32) {
        int row = row0 + am;
        float av8[8];
        if (kb == 0) {
            int xbase = row * TT + t * WW + ak0;
#pragma unroll
            for (int j = 0; j < 8; j++) av8[j] = ld3(x, xbase + j, m0);
        } else {
            const float* hp = h + (size_t)row * 128 + (kb - 32) + ak0;
            float4 a0 = *(const float4*)hp;
            float4 a1 = *(const float4*)(hp + 4);
            av8[0] = a0.x; av8[1] = a0.y; av8[2] = a0.z; av8[3] = a0.w;
            av8[4] = a1.x; av8[5] = a1.y; av8[6] = a1.z; av8[7] = a1.w;
        }
#pragma unroll
        for (int jj = 0; jj < 8; jj++) { int j = (jj + rot) & 7; As[ak0 + j][am] = av8[j]; }
        const float* bp = Wgf + (size_t)(kb + bk) * 64 + bn0;
        *(float4*)&Bs[bk][bn0]     = *(const float4*)bp;
        *(float4*)&Bs[bk][bn0 + 4] = *(const float4*)(bp + 4);
        __syncthreads();
#pragma unroll
        for (int kk = 0; kk < 32; kk++) {
            float4 av = *(const float4*)&As[kk][tm * 4];
            float4 bv = *(const float4*)&Bs[kk][tn * 4];
            float aa[4] = {av.x, av.y, av.z, av.w};
            float bb[4] = {bv.x, bv.y, bv.z, bv.w};
#pragma unroll
            for (int i = 0; i < 4; i++)
#pragma unroll
                for (int j = 0; j < 4; j++) acc[i][j] += aa[i] * bb[j];
        }
        __syncthreads();
    }
    bool rnd = (t == 0 && m0 == 0 && modes[3] == 0);
#pragma unroll
    for (int i = 0; i < 4; i++) {
        int row = row0 + tm * 4 + i;
#pragma unroll
        for (int j = 0; j < 4; j++) {
            float v = acc[i][j];
            Y[(size_t)row * 64 + tn * 4 + j] = rnd ? r16(v) : v;
        }
    }
}

// k23g: fused k2+k3. tile 32 c-rows x 64 f. grid (8, BB). Also zeros qsum.
__global__ __launch_bounds__(256) void k23g(const float* St, const float* Y,
                                            const __hip_bfloat16* bg,
                                            const float* W1f, const float* W2f,
                                            const __hip_bfloat16* b1, const __hip_bfloat16* b2,
                                            float* de1, float* de2, float* qsum,
                                            int t, const int* modes) {
    __shared__ float As[32][36];
    __shared__ float Bs[32][68];
    __shared__ float dfT[64][36];
    int b = blockIdx.y, c0 = blockIdx.x * 32;
    int tid = threadIdx.x;
    if (blockIdx.x == 0) qsum[b * NN + tid] = 0.f;
    int tm = tid >> 4, tn = tid & 15;
    int am = tid & 31, ak0 = (tid >> 5) * 4;
    int bk = tid >> 3, bn0 = (tid & 7) * 8;
    const float* Yb = Y + (size_t)b * (NN * EMBD);
    float acc[2][4] = {};
    for (int kb = 0; kb < 256; kb += 32) {
        float4 a0 = *(const float4*)(St + (size_t)(c0 + am) * 256 + kb + ak0);
        float av4[4] = {a0.x, a0.y, a0.z, a0.w};
        int rot = (tid >> 5) & 3;
#pragma unroll
        for (int jj = 0; jj < 4; jj++) { int j = (jj + rot) & 3; As[ak0 + j][am] = av4[j]; }
        const float* bp = Yb + (size_t)(kb + bk) * 64 + bn0;
        *(float4*)&Bs[bk][bn0]     = *(const float4*)bp;
        *(float4*)&Bs[bk][bn0 + 4] = *(const float4*)(bp + 4);
        __syncthreads();
#pragma unroll
        for (int kk = 0; kk < 32; kk++) {
            float2 av = *(const float2*)&As[kk][tm * 2];
            float4 bv = *(const float4*)&Bs[kk][tn * 4];
            float aa[2] = {av.x, av.y};
            float bb[4] = {bv.x, bv.y, bv.z, bv.w};
#pragma unroll
            for (int i = 0; i < 2; i++)
#pragma unroll
                for (int j = 0; j < 4; j++) acc[i][j] += aa[i] * bb[j];
        }
        __syncthreads();
    }
    bool rnd = (t == 0 && modes[0] == 0 && modes[3] == 0);
#pragma unroll
    for (int i = 0; i < 2; i++)
#pragma unroll
        for (int j = 0; j < 4; j++) {
            int f = tn * 4 + j;
            dfT[f][tm * 2 + i] = (rnd ? r16(acc[i][j]) : acc[i][j]) + bf(bg, f);
        }
    __syncthreads();
    float a1acc[2][4] = {};
    for (int kb2 = 0; kb2 < 64; kb2 += 32) {
        const float* bp = W1f + (size_t)(kb2 + bk) * 64 + bn0;
        *(float4*)&Bs[bk][bn0]     = *(const float4*)bp;
        *(float4*)&Bs[bk][bn0 + 4] = *(const float4*)(bp + 4);
        __syncthreads();
#pragma unroll
        for (int kk = 0; kk < 32; kk++) {
            float2 av = *(const float2*)&dfT[kb2 + kk][tm * 2];
            float4 bv = *(const float4*)&Bs[kk][tn * 4];
            float aa[2] = {av.x, av.y};
            float bb[4] = {bv.x, bv.y, bv.z, bv.w};
#pragma unroll
            for (int i = 0; i < 2; i++)
#pragma unroll
                for (int j = 0; j < 4; j++) a1acc[i][j] += aa[i] * bb[j];
        }
        __syncthreads();
    }
#pragma unroll
    for (int i = 0; i < 2; i++) {
        int row = b * NN + c0 + tm * 2 + i;
        float4 o;
        o.x = tanh_s(a1acc[i][0] + bf(b1, tn * 4 + 0));
        o.y = tanh_s(a1acc[i][1] + bf(b1, tn * 4 + 1));
        o.z = tanh_s(a1acc[i][2] + bf(b1, tn * 4 + 2));
        o.w = tanh_s(a1acc[i][3] + bf(b1, tn * 4 + 3));
        *(float4*)&de1[(size_t)row * 64 + tn * 4] = o;
    }
    float a2acc[2][4] = {};
    for (int kb2 = 0; kb2 < 64; kb2 += 32) {
        const float* bp = W2f + (size_t)(kb2 + bk) * 64 + bn0;
        *(float4*)&Bs[bk][bn0]     = *(const float4*)bp;
        *(float4*)&Bs[bk][bn0 + 4] = *(const float4*)(bp + 4);
        __syncthreads();
#pragma unroll
        for (int kk = 0; kk < 32; kk++) {
            float2 av = *(const float2*)&dfT[kb2 + kk][tm * 2];
            float4 bv = *(const float4*)&Bs[kk][tn * 4];
            float aa[2] = {av.x, av.y};
            float bb[4] = {bv.x, bv.y, bv.z, bv.w};
#pragma unroll
            for (int i = 0; i < 2; i++)
#pragma unroll
                for (int j = 0; j < 4; j++) a2acc[i][j] += aa[i] * bb[j];
        }
        __syncthreads();
    }
#pragma unroll
    for (int i = 0; i < 2; i++) {
        int row = b * NN + c0 + tm * 2 + i;
        float4 o;
        o.x = tanh_s(a2acc[i][0] + bf(b2, tn * 4 + 0));
        o.y = tanh_s(a2acc[i][1] + bf(b2, tn * 4 + 1));
        o.z = tanh_s(a2acc[i][2] + bf(b2, tn * 4 + 2));
        o.w = tanh_s(a2acc[i][3] + bf(b2, tn * 4 + 3));
        *(float4*)&de2[(size_t)row * 64 + tn * 4] = o;
    }
}

// k45: fused M+Et+hist+AhT+qsum. grid (4,4,BB). M never hits global.
__global__ __launch_bounds__(256) void k45(const float* de1, const float* de2,
                                           float* hist, float* AhT, float* qsum,
                                           int slabW, int slabR, float inv_cnt) {
    __shared__ float As[32][68];
    __shared__ float Bs[32][68];
    __shared__ float m2b[64][65];
    __shared__ float qpart[64];
    int b = blockIdx.z, r0 = blockIdx.x * 64, c0 = blockIdx.y * 64;
    int tid = threadIdx.x;
    if (tid < 64) qpart[tid] = 0.f;
    int tn = tid & 15, tm = tid >> 4;
    int am = tid >> 2, ak0 = (tid & 3) * 8;
    int rot = (tid & 3) * 2;
    const float* d1 = de1 + (size_t)b * (NN * EMBD);
    const float* d2 = de2 + (size_t)b * (NN * EMBD);
    float acc2[4][4] = {};
    for (int kb = 0; kb < 64; kb += 32) {
        const float* ap = d1 + (size_t)(c0 + am) * 64 + kb + ak0;
        float4 a0 = *(const float4*)ap;
        float4 a1 = *(const float4*)(ap + 4);
        float av8[8] = {a0.x, a0.y, a0.z, a0.w, a1.x, a1.y, a1.z, a1.w};
#pragma unroll
        for (int jj = 0; jj < 8; jj++) { int j = (jj + rot) & 7; As[ak0 + j][am] = av8[j]; }
        const float* bp = d2 + (size_t)(r0 + am) * 64 + kb + ak0;
        float4 b0 = *(const float4*)bp;
        float4 b1v = *(const float4*)(bp + 4);
        float bv8[8] = {b0.x, b0.y, b0.z, b0.w, b1v.x, b1v.y, b1v.z, b1v.w};
#pragma unroll
        for (int jj = 0; jj < 8; jj++) { int j = (jj + rot) & 7; Bs[ak0 + j][am] = bv8[j]; }
        __syncthreads();
#pragma unroll
        for (int kk = 0; kk < 32; kk++) {
            float4 av = *(const float4*)&As[kk][tm * 4];
            float4 bv = *(const float4*)&Bs[kk][tn * 4];
            float aa[4] = {av.x, av.y, av.z, av.w};
            float bb[4] = {bv.x, bv.y, bv.z, bv.w};
#pragma unroll
            for (int i = 0; i < 4; i++)
#pragma unroll
                for (int j = 0; j < 4; j++) acc2[i][j] += aa[i] * bb[j];
        }
        __syncthreads();
    }
#pragma unroll
    for (int i = 0; i < 4; i++)
#pragma unroll
        for (int j = 0; j < 4; j++) m2b[tm * 4 + i][tn * 4 + j] = acc2[i][j];
    float acc1[4][4] = {};
    for (int kb = 0; kb < 64; kb += 32) {
        const float* ap = d1 + (size_t)(r0 + am) * 64 + kb + ak0;
        float4 a0 = *(const float4*)ap;
        float4 a1 = *(const float4*)(ap + 4);
        float av8[8] = {a0.x, a0.y, a0.z, a0.w, a1.x, a1.y, a1.z, a1.w};
#pragma unroll
        for (int jj = 0; jj < 8; jj++) { int j = (jj + rot) & 7; As[ak0 + j][am] = av8[j]; }
        const float* bp = d2 + (size_t)(c0 + am) * 64 + kb + ak0;
        float4 b0 = *(const float4*)bp;
        float4 b1v = *(const float4*)(bp + 4);
        float bv8[8] = {b0.x, b0.y, b0.z, b0.w, b1v.x, b1v.y, b1v.z, b1v.w};
#pragma unroll
        for (int jj = 0; jj < 8; jj++) { int j = (jj + rot) & 7; Bs[ak0 + j][am] = bv8[j]; }
        __syncthreads();
#pragma unroll
        for (int kk = 0; kk < 32; kk++) {
            float4 av = *(const float4*)&As[kk][tm * 4];
            float4 bv = *(const float4*)&Bs[kk][tn * 4];
            float aa[4] = {av.x, av.y, av.z, av.w};
            float bb[4] = {bv.x, bv.y, bv.z, bv.w};
#pragma unroll
            for (int i = 0; i < 4; i++)
#pragma unroll
                for (int j = 0; j < 4; j++) acc1[i][j] += aa[i] * bb[j];
        }
        __syncthreads();
    }
    size_t NB = (size_t)BB * NN * NN;
    float* hsW = hist + (size_t)slabW * NB;
    const float* hsR = hist + (size_t)slabR * NB;
    float ad[4][4];
#pragma unroll
    for (int i = 0; i < 4; i++) {
        int r = r0 + tm * 4 + i;
        size_t o = ((size_t)(b * NN + r)) * NN + c0 + tn * 4;
        float4 e2v = *(const float4*)&hsW[o];
        float4 e1v = *(const float4*)&hsR[o];
        float e2a[4] = {e2v.x, e2v.y, e2v.z, e2v.w};
        float e1a[4] = {e1v.x, e1v.y, e1v.z, e1v.w};
        float4 ew4;
        float eo[4];
#pragma unroll
        for (int j = 0; j < 4; j++) {
            int c = c0 + tn * 4 + j;
            float e = tanh_s(acc1[i][j] - m2b[tn * 4 + j][tm * 4 + i]);
            e = e > 0.f ? e : 0.f;
            eo[j] = e;
            float mt = (e + e1a[j] + e2a[j]) * inv_cnt;
            float adv = (mt > 1e-8f) ? mt : 0.f;
            if (r == c) adv += 1.f;
            ad[i][j] = adv;
        }
        ew4.x = eo[0]; ew4.y = eo[1]; ew4.z = eo[2]; ew4.w = eo[3];
        *(float4*)&hsW[o] = ew4;
    }
#pragma unroll
    for (int j = 0; j < 4; j++) {
        float cs = ad[0][j] + ad[1][j] + ad[2][j] + ad[3][j];
        atomicAdd(&qpart[tn * 4 + j], cs);
    }
    __syncthreads();
#pragma unroll
    for (int i = 0; i < 4; i++)
#pragma unroll
        for (int j = 0; j < 4; j++) m2b[tn * 4 + j][tm * 4 + i] = ad[i][j];
    __syncthreads();
#pragma unroll
    for (int kk = 0; kk < 4; kk++) {
        int e = tid + kk * 256;
        int cl = e >> 4, q4 = e & 15;
        float4 o;
        o.x = m2b[cl][q4 * 4 + 0]; o.y = m2b[cl][q4 * 4 + 1];
        o.z = m2b[cl][q4 * 4 + 2]; o.w = m2b[cl][q4 * 4 + 3];
        *(float4*)&AhT[((size_t)(b * NN + c0 + cl)) * NN + r0 + q4 * 4] = o;
    }
    if (tid < 64) atomicAdd(&qsum[b * NN + c0 + tid], qpart[tid]);
}

// k8f: fused k8a+k8b. grid (8, BB): 32 c-rows per block.
// Phase1: G[c][w] = q[c]*sum_r AhT[c,r]*q[r]*vt[r,w] -> LDS.
// Phase2: C[row, 0..383] = G@Wall + bias (3 chunks of 128 cols).
__global__ __launch_bounds__(256) void k8f(const float* AhT, const void* x, const float* qsum,
                                           const float* Wall,
                                           const __hip_bfloat16* bz, const __hip_bfloat16* br,
                                           const __hip_bfloat16* bh, float* C,
                                           int t, const int* modes) {
    __shared__ float As[32][36];
    __shared__ float Bs[32][36];
    __shared__ float Gs[32][33];
    __shared__ float Bs2[32][132];
    int b = blockIdx.y, c0 = blockIdx.x * 32;
    int tid = threadIdx.x;
    int m0 = modes[0];
    const float* Ab = AhT + (size_t)b * (NN * NN);
    // phase 1
    {
        int tm = tid >> 3, tn = tid & 7;
        int am = tid & 31, ak0 = (tid >> 5) * 4;
        int rB = tid >> 3, w0 = (tid & 7) * 4;
        float acc[4] = {0, 0, 0, 0};
        for (int kb = 0; kb < 256; kb += 32) {
            float4 a0 = *(const float4*)(Ab + (size_t)(c0 + am) * 256 + kb + ak0);
            float av4[4] = {a0.x, a0.y, a0.z, a0.w};
            int rotA = (tid >> 5) & 3;
#pragma unroll
            for (int jj = 0; jj < 4; jj++) { int j = (jj + rotA) & 3; As[ak0 + j][am] = av4[j]; }
            int r = kb + rB;
            float qr = 1.0f / sqrtf(fmaxf(qsum[b * NN + r], 1e-12f));
            int xbase = (b * NN + r) * TT + t * WW + w0;
            float pv[4];
#pragma unroll
            for (int i = 0; i < 4; i++) pv[i] = qr * ld3(x, xbase + i, m0);
            int rot = rB & 3;
#pragma unroll
            for (int i = 0; i < 4; i++) { int j = (i + rot) & 3; Bs[rB][w0 + j] = pv[j]; }
            __syncthreads();
#pragma unroll
            for (int kk = 0; kk < 32; kk++) {
                float a = As[kk][tm];
                float4 bv = *(const float4*)&Bs[kk][tn * 4];
                acc[0] += a * bv.x; acc[1] += a * bv.y;
                acc[2] += a * bv.z; acc[3] += a * bv.w;
            }
            __syncthreads();
        }
        float qc = 1.0f / sqrtf(fmaxf(qsum[b * NN + c0 + tm], 1e-12f));
#pragma unroll
        for (int i = 0; i < 4; i++) Gs[tm][tn * 4 + i] = qc * acc[i];
    }
    __syncthreads();
    // phase 2: 3 chunks of 128 columns
    {
        int tm = tid >> 5, tn = tid & 31;          // rows tm*4..+3 (32), cols tn*4..+3 (128)
        int bk = tid >> 3, bn0 = (tid & 7) * 16;
        for (int jc = 0; jc < 3; jc++) {
            int j0 = jc * 128;
            const float* bp = Wall + (size_t)bk * 384 + j0 + bn0;
            *(float4*)&Bs2[bk][bn0]      = *(const float4*)bp;
            *(float4*)&Bs2[bk][bn0 + 4]  = *(const float4*)(bp + 4);
            *(float4*)&Bs2[bk][bn0 + 8]  = *(const float4*)(bp + 8);
            *(float4*)&Bs2[bk][bn0 + 12] = *(const float4*)(bp + 12);
            __syncthreads();
            float acc[4][4] = {};
#pragma unroll
            for (int kk = 0; kk < 32; kk++) {
                float aa[4];
#pragma unroll
                for (int i = 0; i < 4; i++) aa[i] = Gs[tm * 4 + i][kk];
                float4 bv = *(const float4*)&Bs2[kk][tn * 4];
                float bb[4] = {bv.x, bv.y, bv.z, bv.w};
#pragma unroll
                for (int i = 0; i < 4; i++)
#pragma unroll
                    for (int j = 0; j < 4; j++) acc[i][j] += aa[i] * bb[j];
            }
            const __hip_bfloat16* bias = (jc == 0) ? bz : ((jc == 1) ? br : bh);
#pragma unroll
            for (int i = 0; i < 4; i++) {
                int row = b * NN + c0 + tm * 4 + i;
                float4 o;
                o.x = acc[i][0] + bf(bias, tn * 4 + 0);
                o.y = acc[i][1] + bf(bias, tn * 4 + 1);
                o.z = acc[i][2] + bf(bias, tn * 4 + 2);
                o.w = acc[i][3] + bf(bias, tn * 4 + 3);
                *(float4*)&C[(size_t)row * 384 + j0 + tn * 4] = o;
            }
            __syncthreads();
        }
    }
}

// k9f: fused GRU gates. tile 32 rows x 128 f, grid 256 blocks.
// Z,R,Ht GEMMs (K=256) with Z,hR in LDS only; h updated in place.
__global__ __launch_bounds__(256) void k9f(const float* C, float* h,
                                           const float* Wlzf, const float* Wlrf,
                                           const float* Wlhf,
                                           const __hip_bfloat16* blz, const __hip_bfloat16* blr,
                                           const __hip_bfloat16* blh) {
    __shared__ float As[32][36];
    __shared__ float Bs[32][132];
    __shared__ float Zs[32][133];
    __shared__ float hRs[32][133];
    int row0 = blockIdx.x * 32;
    int tid = threadIdx.x;
    int tm = tid >> 5, tn = tid & 31;      // out rows tm*4..+3, f tn*4..+3
    int am = tid & 31, ak0 = (tid >> 5) * 4;
    int bk = tid >> 3, bn0 = (tid & 7) * 16;
    // ---- gate Z (ofs 0) then R (ofs 128) ----
    for (int gate = 0; gate < 2; gate++) {
        const float* W = gate ? Wlrf : Wlzf;
        int cofs = gate * 128;
        float acc[4][4] = {};
        for (int kb = 0; kb < 256; kb += 32) {
            int kpos = kb + ak0;
            const float* ap = (kpos < 128)
                ? (C + (size_t)(row0 + am) * 384 + cofs + kpos)
                : (h + (size_t)(row0 + am) * 128 + (kpos - 128));
            float4 a0 = *(const float4*)ap;
            As[ak0 + 0][am] = a0.x; As[ak0 + 1][am] = a0.y;
            As[ak0 + 2][am] = a0.z; As[ak0 + 3][am] = a0.w;
            const float* bp = W + (size_t)(kb + bk) * 128 + bn0;
            *(float4*)&Bs[bk][bn0]      = *(const float4*)bp;
            *(float4*)&Bs[bk][bn0 + 4]  = *(const float4*)(bp + 4);
            *(float4*)&Bs[bk][bn0 + 8]  = *(const float4*)(bp + 8);
            *(float4*)&Bs[bk][bn0 + 12] = *(const float4*)(bp + 12);
            __syncthreads();
#pragma unroll
            for (int kk = 0; kk < 32; kk++) {
                float aa[4];
#pragma unroll
                for (int i = 0; i < 4; i++) aa[i] = As[kk][tm * 4 + i];
                float4 bv = *(const float4*)&Bs[kk][tn * 4];
                float bb[4] = {bv.x, bv.y, bv.z, bv.w};
#pragma unroll
                for (int i = 0; i < 4; i++)
#pragma unroll
                    for (int j = 0; j < 4; j++) acc[i][j] += aa[i] * bb[j];
            }
            __syncthreads();
        }
        const __hip_bfloat16* bias = gate ? blr : blz;
#pragma unroll
        for (int i = 0; i < 4; i++) {
            int rl = tm * 4 + i;
#pragma unroll
            for (int j = 0; j < 4; j++) {
                int f = tn * 4 + j;
                float v = sig_s(acc[i][j] + bf(bias, f));
                if (gate == 0) Zs[rl][f] = v;
                else           hRs[rl][f] = h[(size_t)(row0 + rl) * 128 + f] * v;
            }
        }
        __syncthreads();
    }
    // ---- gate Ht: A = [C_h | hRs] ----
    float acc[4][4] = {};
    for (int kb = 0; kb < 256; kb += 32) {
        int kpos = kb + ak0;
        if (kpos < 128) {
            const float* ap = C + (size_t)(row0 + am) * 384 + 256 + kpos;
            float4 a0 = *(const float4*)ap;
            As[ak0 + 0][am] = a0.x; As[ak0 + 1][am] = a0.y;
            As[ak0 + 2][am] = a0.z; As[ak0 + 3][am] = a0.w;
        } else {
#pragma unroll
            for (int j = 0; j < 4; j++) As[ak0 + j][am] = hRs[am][kpos - 128 + j];
        }
        const float* bp = Wlhf + (size_t)(kb + bk) * 128 + bn0;
        *(float4*)&Bs[bk][bn0]      = *(const float4*)bp;
        *(float4*)&Bs[bk][bn0 + 4]  = *(const float4*)(bp + 4);
        *(float4*)&Bs[bk][bn0 + 8]  = *(const float4*)(bp + 8);
        *(float4*)&Bs[bk][bn0 + 12] = *(const float4*)(bp + 12);
        __syncthreads();
#pragma unroll
        for (int kk = 0; kk < 32; kk++) {
            float aa[4];
#pragma unroll
            for (int i = 0; i < 4; i++) aa[i] = As[kk][tm * 4 + i];
            float4 bv = *(const float4*)&Bs[kk][tn * 4];
            float bb[4] = {bv.x, bv.y, bv.z, bv.w};
#pragma unroll
            for (int i = 0; i < 4; i++)
#pragma unroll
                for (int j = 0; j < 4; j++) acc[i][j] += aa[i] * bb[j];
        }
        __syncthreads();
    }
#pragma unroll
    for (int i = 0; i < 4; i++) {
        int rl = tm * 4 + i;
        size_t ro = (size_t)(row0 + rl) * 128;
        float4 hv = *(const float4*)&h[ro + tn * 4];
        float ha[4] = {hv.x, hv.y, hv.z, hv.w};
        float4 o;
        float ov[4];
#pragma unroll
        for (int j = 0; j < 4; j++) {
            int f = tn * 4 + j;
            float Ht = tanh_s(acc[i][j] + bf(blh, f));
            float z = Zs[rl][f];
            ov[j] = z * ha[j] + (1.0f - z) * Ht;
        }
        o.x = ov[0]; o.y = ov[1]; o.z = ov[2]; o.w = ov[3];
        *(float4*)&h[ro + tn * 4] = o;
    }
}

__global__ __launch_bounds__(256) void k10a(const float* h, const float* Wcf, float* partial) {
    __shared__ float red[16][17];
    int chunk = blockIdx.x, b = blockIdx.y;
    int c = threadIdx.x & 15, isub = threadIdx.x >> 4;
    const float* hb = h + (size_t)b * (NN * HH);
    int i0 = chunk * 2048;
    float acc = 0.f;
    for (int s = 0; s < 128; s++) {
        int i = i0 + isub + 16 * s;
        acc += hb[i] * Wcf[(size_t)i * NCLS + c];
    }
    red[isub][c] = acc;
    __syncthreads();
    for (int st = 8; st > 0; st >>= 1) {
        if (isub < st) red[isub][c] += red[isub + st][c];
        __syncthreads();
    }
    if (isub == 0) partial[((size_t)(b * NCLS + c)) * 16 + chunk] = red[0][c];
}

__global__ __launch_bounds__(512) void k10b(const float* partial, const __hip_bfloat16* bcb,
                                            float* out) {
    int tid = threadIdx.x;
    if (tid < BB * NCLS) {
        int c = tid & 15;
        float s = 0.f;
        for (int k = 0; k < 16; k++) s += partial[(size_t)tid * 16 + k];
        out[tid] = s + bf(bcb, c);
    }
}

// ---------------- launch ----------------

extern "C" void kernel_launch(void* const* d_in, const int* in_sizes, int n_in,
                              void* d_out, int out_size, void* d_ws, size_t ws_size,
                              hipStream_t stream) {
    float* out = (float*)d_out;

    static const int exp_sizes[23] = {2097152, 16384, 8192, 10240, 64, 4096, 64, 4096, 64,
                                      4096, 128, 4096, 128, 4096, 128, 32768, 128, 32768, 128,
                                      32768, 128, 524288, 16};
    if (n_in != 23) { k_sentinel<<<8, 64, 0, stream>>>(out, 4444.0f); return; }
    for (int i = 0; i < 23; i++) {
        if (in_sizes[i] != exp_sizes[i]) {
            k_sentinel<<<8, 64, 0, stream>>>(out, (float)(4000 + i));
            return;
        }
    }

    const void* x   = d_in[0];
    const int*  ei  = (const int*)d_in[1];
    const void* ew  = d_in[2];
    const void* Wg  = d_in[3];
    const __hip_bfloat16* bg  = (const __hip_bfloat16*)d_in[4];
    const void* W1  = d_in[5];
    const __hip_bfloat16* b1  = (const __hip_bfloat16*)d_in[6];
    const void* W2  = d_in[7];
    const __hip_bfloat16* b2  = (const __hip_bfloat16*)d_in[8];
    const void* Wz  = d_in[9];
    const __hip_bfloat16* bz  = (const __hip_bfloat16*)d_in[10];
    const void* Wr  = d_in[11];
    const __hip_bfloat16* br  = (const __hip_bfloat16*)d_in[12];
    const void* Wh  = d_in[13];
    const __hip_bfloat16* bh  = (const __hip_bfloat16*)d_in[14];
    const void* Wlz = d_in[15];
    const __hip_bfloat16* blz = (const __hip_bfloat16*)d_in[16];
    const void* Wlr = d_in[17];
    const __hip_bfloat16* blr = (const __hip_bfloat16*)d_in[18];
    const void* Wlh = d_in[19];
    const __hip_bfloat16* blh = (const __hip_bfloat16*)d_in[20];
    const void* Wc  = d_in[21];
    const __hip_bfloat16* bcb = (const __hip_bfloat16*)d_in[22];

    float* ws = (float*)d_ws;
    const size_t off_A    = 0;
    const size_t off_hist = off_A + 65536;
    const size_t off_h    = off_hist + 2u * 2097152;
    const size_t off_flag = off_h + 1048576;
    const size_t off_mode = off_flag + 16;
    const size_t off_insB = off_mode + 32;
    const size_t off_insF = off_insB + 32;
    const size_t zero_end = off_insF + 32;
    const size_t off_St   = zero_end;
    const size_t off_di   = off_St + 65536;
    const size_t off_q    = off_di + 256;
    const size_t off_AhT  = off_q + 8192;
    const size_t off_Yp   = off_AhT + 2097152;
    const size_t off_C    = off_Yp + 3145728;
    const size_t off_wts  = off_C + 3145728;
    const size_t need_bytes = (off_wts + 665600u) * sizeof(float);

    if (ws_size < need_bytes) {
        k_sentinel<<<8, 64, 0, stream>>>(out, (float)ws_size);
        return;
    }

    float* A    = ws + off_A;
    float* hist = ws + off_hist;
    float* h    = ws + off_h;
    int*   modes= (int*)(ws + off_mode);
    int*   insB = (int*)(ws + off_insB);
    int*   insF = (int*)(ws + off_insF);
    float* St   = ws + off_St;
    float* di   = ws + off_di;
    float* qsum = ws + off_q;
    float* AhT  = ws + off_AhT;
    float* C    = ws + off_C;
    float* wts  = ws + off_wts;
    float* Y    = ws + off_Yp;
    float* de1  = ws + off_Yp + 1048576;
    float* de2  = ws + off_Yp + 1572864;
    float* partial = qsum;

    float* Wgf  = wts;
    float* W1f  = wts + 10240;
    float* W2f  = wts + 14336;
    float* Wlzf = wts + 30720;
    float* Wlrf = wts + 63488;
    float* Wlhf = wts + 96256;
    float* Wcf  = wts + 129024;
    float* Wall = wts + 653312;

    hipMemsetAsync(ws, 0, zero_end * sizeof(float), stream);

    k_probe_all<<<48, 256, 0, stream>>>(x, ew, Wg, W1, W2, Wz, Wr, Wh, Wlz, Wlr, Wlh, Wc,
                                        insB, insF);
    k_resolve<<<1, 32, 0, stream>>>(insB, insF, modes);
    k_detect_ei<<<1, 64, 0, stream>>>(ei, modes);
    k_cvtall<<<2600, 256, 0, stream>>>(Wg, W1, W2, Wz, Wr, Wh, Wlz, Wlr, Wlh, Wc, modes, wts);

    k_scatter<<<NE / 256, 256, 0, stream>>>(ei, ew, A, modes);
    k_roundA<<<NN * NN / 256, 256, 0, stream>>>(A);
    k_di<<<NN / 4, 256, 0, stream>>>(A, di);
    k_St<<<NN * NN / 256, 256, 0, stream>>>(A, di, St);

    for (int t = 0; t < 8; t++) {
        k1g<<<128, 256, 0, stream>>>(x, h, Wgf, Y, t, modes);
        k23g<<<dim3(8, BB), 256, 0, stream>>>(St, Y, bg, W1f, W2f, b1, b2,
                                              de1, de2, qsum, t, modes);
        float inv_cnt = 1.0f / (float)((t + 1 < 3) ? (t + 1) : 3);
        k45<<<dim3(4, 4, BB), 256, 0, stream>>>(de1, de2, hist, AhT, qsum,
                                                t & 1, (t + 1) & 1, inv_cnt);
        k8f<<<dim3(8, BB), 256, 0, stream>>>(AhT, x, qsum, Wall, bz, br, bh, C, t, modes);
        k9f<<<256, 256, 0, stream>>>(C, h, Wlzf, Wlrf, Wlhf, blz, blr, blh);
    }

    k10a<<<dim3(16, BB), 256, 0, stream>>>(h, Wcf, partial);
    k10b<<<1, 512, 0, stream>>>(partial, bcb, out);
}